// Round 1
// baseline (2174.577 us; speedup 1.0000x reference)
//
#include <hip/hip_runtime.h>
#include <hip/hip_bf16.h>

// CRF forward (partition function) on MI355X.
// Strategy: prob-domain recurrence p' = exp(y)*(E·p)/s with running log-offset,
// E=exp(trans) held in registers (fp16x2, 128 VGPRs/thread), p broadcast via LDS,
// v_dot2_f32_f16 inner product. One block per batch (sequential chain), thread k
// owns output state k.

typedef _Float16 h2 __attribute__((ext_vector_type(2)));
typedef _Float16 h8 __attribute__((ext_vector_type(8)));

#define TT 2048
#define KK 256
#define NTHREADS 256
#define SOS_IDX 2

#if __has_builtin(__builtin_amdgcn_fdot2)
#define FDOT2(a, b, c) __builtin_amdgcn_fdot2((a), (b), (c), false)
#else
#define FDOT2(a, b, c) ((c) + (float)(a)[0] * (float)(b)[0] + (float)(a)[1] * (float)(b)[1])
#endif

__global__ __launch_bounds__(NTHREADS, 1)
void crf_fwd_kernel(const float* __restrict__ y, const float* __restrict__ mask,
                    const float* __restrict__ trans, float* __restrict__ out) {
    const int b = blockIdx.x;
    const int k = threadIdx.x;      // state owned by this thread
    const int lane = k & 63;
    const int wave = k >> 6;

    __shared__ __align__(16) _Float16 P[KK];  // current probs (normalized), fp16
    __shared__ float red[8];                  // cross-wave reduction scratch

    // ---- E row k = exp(trans[k, :]) resident in registers as 128 packed fp16 pairs
    h2 e[KK / 2];
    {
        const float4* tr = (const float4*)(trans + (size_t)k * KK);
        #pragma unroll
        for (int i = 0; i < KK / 4; ++i) {
            float4 v = tr[i];
            h2 a, c;
            a[0] = (_Float16)__expf(v.x);
            a[1] = (_Float16)__expf(v.y);
            c[0] = (_Float16)__expf(v.z);
            c[1] = (_Float16)__expf(v.w);
            e[2 * i] = a;
            e[2 * i + 1] = c;
        }
    }

    // ---- sequence length L = sum(mask[b, :]) (mask is monotone 1...1 0...0)
    float lsum = 0.f;
    {
        const float* mrow = mask + (size_t)b * TT;
        #pragma unroll
        for (int i = 0; i < TT / NTHREADS; ++i) lsum += mrow[k + i * NTHREADS];
        #pragma unroll
        for (int off = 32; off >= 1; off >>= 1) lsum += __shfl_xor(lsum, off, 64);
        if (lane == 0) red[wave] = lsum;
    }

    // ---- init: score0 = NEG everywhere except SOS=0  ->  p = one-hot(SOS), offset 0
    float pf = (k == SOS_IDX) ? 1.f : 0.f;
    P[k] = (_Float16)pf;
    float offset = 0.f;
    __syncthreads();
    const int L = (int)(red[0] + red[1] + red[2] + red[3] + 0.5f);

    const float* yrow = y + (size_t)b * TT * KK + k;
    float ycur = (L > 0) ? yrow[0] : 0.f;

    for (int t = 0; t < L; ++t) {
        // prefetch next emission early (HBM/L2 latency hidden behind dot loop)
        float ynext = (t + 1 < L) ? yrow[(size_t)(t + 1) * KK] : 0.f;

        // q_k = dot(E[k,:], p[:])  — 128 x v_dot2_f32_f16, 4 accumulators
        float q0 = 0.f, q1 = 0.f, q2 = 0.f, q3 = 0.f;
        const h8* Pv = (const h8*)P;   // broadcast ds_read_b128 (conflict-free)
        #pragma unroll
        for (int c = 0; c < KK / 8; ++c) {
            h8 pv = Pv[c];
            h2 p0 = {pv[0], pv[1]}, p1 = {pv[2], pv[3]};
            h2 p2 = {pv[4], pv[5]}, p3 = {pv[6], pv[7]};
            q0 = FDOT2(e[4 * c + 0], p0, q0);
            q1 = FDOT2(e[4 * c + 1], p1, q1);
            q2 = FDOT2(e[4 * c + 2], p2, q2);
            q3 = FDOT2(e[4 * c + 3], p3, q3);
        }
        float q = (q0 + q1) + (q2 + q3);

        // s = max_k q  (wave butterfly + cross-wave via LDS)
        float qm = q;
        #pragma unroll
        for (int off = 32; off >= 1; off >>= 1) qm = fmaxf(qm, __shfl_xor(qm, off, 64));
        if (lane == 0) red[wave] = qm;
        __syncthreads();   // red written; also all P reads of this step done
        float s = fmaxf(fmaxf(red[0], red[1]), fmaxf(red[2], red[3]));

        // p' = exp(y_t) * q / s ;  offset += log(s)
        float pn = __expf(ycur) * q * __builtin_amdgcn_rcpf(s);
        pf = pn;
        P[k] = (_Float16)pn;
        offset += __logf(s);
        ycur = ynext;
        __syncthreads();   // P[k] visible before next step's reads
    }

    // ---- out[b] = offset + log(sum_k p)
    float ssum = pf;
    #pragma unroll
    for (int off = 32; off >= 1; off >>= 1) ssum += __shfl_xor(ssum, off, 64);
    if (lane == 0) red[4 + wave] = ssum;
    __syncthreads();
    if (k == 0) {
        float tot = (red[4] + red[5]) + (red[6] + red[7]);
        out[b] = offset + __logf(tot);
    }
}

extern "C" void kernel_launch(void* const* d_in, const int* in_sizes, int n_in,
                              void* d_out, int out_size, void* d_ws, size_t ws_size,
                              hipStream_t stream) {
    const float* y     = (const float*)d_in[0];   // (B, T, K) fp32
    const float* mask  = (const float*)d_in[1];   // (B, T)    fp32
    const float* trans = (const float*)d_in[2];   // (K, K)    fp32
    float* out = (float*)d_out;                   // (B,)      fp32
    const int B = in_sizes[1] / TT;
    crf_fwd_kernel<<<B, NTHREADS, 0, stream>>>(y, mask, trans, out);
}